// Round 1
// baseline (77.027 us; speedup 1.0000x reference)
//
#include <hip/hip_runtime.h>
#include <hip/hip_bf16.h>

// Problem constants (N,C,H,W) = (32,256,56,56), GROUPS=8
#define NN 32
#define CC 256
#define HH 56
#define WW 56
#define HW 3136            // H*W
#define HW4 784            // HW/4 float4 per (n,c) plane
#define CHW 802816         // C*H*W
#define NCHW 25690112      // total elements
#define NCHW4 6422528      // total float4
#define GROUPS 8
#define CPG 32             // C/GROUPS
#define NHW 100352         // N*H*W  (per-channel count)
#define GHW 100352         // CPG*HW (per-group count)
#define EPSF 1e-5f
#define CHUNKS2 13         // ceil(HW/256) chunks for chansum
#define NB2 (NN*CHUNKS2)   // 416 blocks for chansum

// ---------------- kernel 1: per-(n,c) plane sums S1=sum(x), S2=sum(x^2) -----
__global__ __launch_bounds__(256) void plane_stats_kernel(
    const float4* __restrict__ x4, float* __restrict__ S1, float* __restrict__ S2)
{
    const int b = blockIdx.x;                  // b = n*256 + c
    const float4* p = x4 + (size_t)b * HW4;
    float s1 = 0.f, s2 = 0.f;
    for (int i = threadIdx.x; i < HW4; i += 256) {
        float4 v = p[i];
        s1 += v.x + v.y + v.z + v.w;
        s2 += v.x*v.x + v.y*v.y + v.z*v.z + v.w*v.w;
    }
    #pragma unroll
    for (int off = 32; off; off >>= 1) {
        s1 += __shfl_down(s1, off, 64);
        s2 += __shfl_down(s2, off, 64);
    }
    __shared__ float sh1[4], sh2[4];
    const int wave = threadIdx.x >> 6, lane = threadIdx.x & 63;
    if (lane == 0) { sh1[wave] = s1; sh2[wave] = s2; }
    __syncthreads();
    if (threadIdx.x == 0) {
        S1[b] = sh1[0] + sh1[1] + sh1[2] + sh1[3];
        S2[b] = sh2[0] + sh2[1] + sh2[2] + sh2[3];
    }
}

// ------------- kernel 2: per-position cross-channel sum T, reduce sum(T^2) --
__global__ __launch_bounds__(256) void chansum_kernel(
    const float* __restrict__ x, float* __restrict__ partialT2)
{
    const int n = blockIdx.x / CHUNKS2;
    const int chunk = blockIdx.x % CHUNKS2;
    const int pos = chunk * 256 + threadIdx.x;
    float T = 0.f;
    if (pos < HW) {
        const float* p = x + (size_t)n * CHW + pos;
        #pragma unroll 8
        for (int c = 0; c < CC; ++c) T += p[(size_t)c * HW];
    }
    float t2 = (pos < HW) ? T * T : 0.f;
    #pragma unroll
    for (int off = 32; off; off >>= 1) t2 += __shfl_down(t2, off, 64);
    __shared__ float sh[4];
    const int wave = threadIdx.x >> 6, lane = threadIdx.x & 63;
    if (lane == 0) sh[wave] = t2;
    __syncthreads();
    if (threadIdx.x == 0) partialT2[blockIdx.x] = sh[0] + sh[1] + sh[2] + sh[3];
}

// -------- kernel 3: all stats -> gates -> per-(n,c) affine coeffs A,B -------
__global__ __launch_bounds__(256) void finalize_kernel(
    const float* __restrict__ S1, const float* __restrict__ S2,
    const float* __restrict__ partialT2,
    const float* __restrict__ weight, const float* __restrict__ bias,
    const float* __restrict__ gate_logits, const float* __restrict__ diag_proj,
    float* __restrict__ A, float* __restrict__ B)
{
    const int tid = threadIdx.x;
    __shared__ float sh_mu_b[CC], sh_rs_b[CC];
    __shared__ float sh_mu_g[NN * GROUPS], sh_rs_g[NN * GROUPS];
    __shared__ float sh_mu_l[NN], sh_rs_l[NN];
    __shared__ float sh_red1[4], sh_red2[4], sh_red3[4], sh_red4[4];
    __shared__ float sh_gate[3];

    const float inv_NHW  = 1.f / (float)NHW;
    const float inv_CHW  = 1.f / (float)CHW;
    const float inv_GHW  = 1.f / (float)GHW;
    const float inv_NCHW = 1.f / (float)NCHW;

    // ---- BN: per-channel stats (thread = channel) ----
    const int c = tid;
    float s1 = 0.f, s2 = 0.f;
    for (int n = 0; n < NN; ++n) { s1 += S1[n * CC + c]; s2 += S2[n * CC + c]; }
    const float mu_b  = s1 * inv_NHW;
    const float var_b = s2 * inv_NHW - mu_b * mu_b;
    sh_mu_b[c] = mu_b;
    sh_rs_b[c] = rsqrtf(var_b + EPSF);

    // ---- GN: per-(n,g) stats (thread = n*8+g) ----
    const int ng_n = tid >> 3, ng_g = tid & 7;
    float s1g = 0.f, s2g = 0.f;
    for (int cc = 0; cc < CPG; ++cc) {
        const int idx = ng_n * CC + ng_g * CPG + cc;
        s1g += S1[idx]; s2g += S2[idx];
    }
    const float mu_g  = s1g * inv_GHW;
    const float var_g = s2g * inv_GHW - mu_g * mu_g;
    sh_mu_g[tid] = mu_g;
    sh_rs_g[tid] = rsqrtf(var_g + EPSF);

    // ---- LN: reduce GN sums over the 8 groups of each sample (8 lanes) ----
    float s1l = s1g, s2l = s2g;
    #pragma unroll
    for (int off = 1; off < 8; off <<= 1) {
        s1l += __shfl_xor(s1l, off, 64);
        s2l += __shfl_xor(s2l, off, 64);
    }
    float var_l_contrib = 0.f;
    if (ng_g == 0) {
        const float mu_l  = s1l * inv_CHW;
        const float var_l = s2l * inv_CHW - mu_l * mu_l;
        sh_mu_l[ng_n] = mu_l;
        sh_rs_l[ng_n] = rsqrtf(var_l + EPSF);
        var_l_contrib = var_l;
    }

    // ---- T^2 partials for channel_var ----
    float t2p = 0.f;
    for (int i = tid; i < NB2; i += 256) t2p += partialT2[i];

    // ---- combined block reductions: var_b sum, total x^2 (s2 over c),
    //      var_l sum, T^2 sum ----
    float r1 = var_b, r2 = s2, r3 = var_l_contrib, r4 = t2p;
    #pragma unroll
    for (int off = 32; off; off >>= 1) {
        r1 += __shfl_down(r1, off, 64);
        r2 += __shfl_down(r2, off, 64);
        r3 += __shfl_down(r3, off, 64);
        r4 += __shfl_down(r4, off, 64);
    }
    const int wave = tid >> 6, lane = tid & 63;
    if (lane == 0) { sh_red1[wave] = r1; sh_red2[wave] = r2; sh_red3[wave] = r3; sh_red4[wave] = r4; }
    __syncthreads();
    if (tid == 0) {
        const float sum_var_b = sh_red1[0] + sh_red1[1] + sh_red1[2] + sh_red1[3];
        const float total_x2  = sh_red2[0] + sh_red2[1] + sh_red2[2] + sh_red2[3];
        const float sum_var_l = sh_red3[0] + sh_red3[1] + sh_red3[2] + sh_red3[3];
        const float sum_T2    = sh_red4[0] + sh_red4[1] + sh_red4[2] + sh_red4[3];

        const float batch_var   = sum_var_b * (1.f / (float)CC);
        const float sample_var  = sum_var_l * (1.f / (float)NN);
        const float channel_var = total_x2 * inv_NCHW
                                - sum_T2 * inv_NHW * (1.f / ((float)CC * (float)CC));

        float desc[3];
        desc[0] = tanhf(logf(fmaxf(batch_var,   EPSF)));
        desc[1] = tanhf(logf(fmaxf(sample_var,  EPSF)));
        desc[2] = tanhf(logf(fmaxf(channel_var, EPSF)));

        float lg[3];
        #pragma unroll
        for (int i = 0; i < 3; ++i) {
            lg[i] = gate_logits[i] + diag_proj[i*3+0]*desc[0]
                                   + diag_proj[i*3+1]*desc[1]
                                   + diag_proj[i*3+2]*desc[2];
        }
        const float m = fmaxf(lg[0], fmaxf(lg[1], lg[2]));
        const float e0 = expf(lg[0]-m), e1 = expf(lg[1]-m), e2 = expf(lg[2]-m);
        const float inv = 1.f / (e0 + e1 + e2);
        sh_gate[0] = e0 * inv; sh_gate[1] = e1 * inv; sh_gate[2] = e2 * inv;
    }
    __syncthreads();

    // ---- per-(n,c) affine coefficients ----
    const float g0 = sh_gate[0], g1 = sh_gate[1], g2 = sh_gate[2];
    for (int i = tid; i < NN * CC; i += 256) {
        const int n = i >> 8, ch = i & 255, g = ch >> 5;
        const float w = weight[ch], bi = bias[ch];
        const float rb = sh_rs_b[ch], rl = sh_rs_l[n], rg = sh_rs_g[n*8+g];
        const float mb = sh_mu_b[ch], ml = sh_mu_l[n], mg = sh_mu_g[n*8+g];
        const float scale = g0*rb + g1*rl + g2*rg;
        const float offs  = g0*mb*rb + g1*ml*rl + g2*mg*rg;
        A[i] = w * scale;
        B[i] = bi - w * offs;
    }
}

// ---------------- kernel 4: y = x*A[n,c] + B[n,c]  (float4) -----------------
__global__ __launch_bounds__(256) void apply_kernel(
    const float4* __restrict__ x4, const float* __restrict__ A,
    const float* __restrict__ B, float4* __restrict__ y4)
{
    const int stride = gridDim.x * blockDim.x;
    for (int i = blockIdx.x * 256 + threadIdx.x; i < NCHW4; i += stride) {
        const int nc = i / HW4;               // 784 float4 per plane
        const float a = A[nc], b = B[nc];
        float4 v = x4[i];
        v.x = v.x * a + b;
        v.y = v.y * a + b;
        v.z = v.z * a + b;
        v.w = v.w * a + b;
        y4[i] = v;
    }
}

extern "C" void kernel_launch(void* const* d_in, const int* in_sizes, int n_in,
                              void* d_out, int out_size, void* d_ws, size_t ws_size,
                              hipStream_t stream) {
    const float* x           = (const float*)d_in[0];
    const float* weight      = (const float*)d_in[1];
    const float* bias        = (const float*)d_in[2];
    const float* gate_logits = (const float*)d_in[3];
    const float* diag_proj   = (const float*)d_in[4];
    float* out = (float*)d_out;

    float* ws  = (float*)d_ws;
    float* S1  = ws;            // 8192
    float* S2  = ws + 8192;     // 8192
    float* A   = ws + 16384;    // 8192
    float* B   = ws + 24576;    // 8192
    float* pT2 = ws + 32768;    // 416

    plane_stats_kernel<<<NN * CC, 256, 0, stream>>>((const float4*)x, S1, S2);
    chansum_kernel<<<NB2, 256, 0, stream>>>(x, pT2);
    finalize_kernel<<<1, 256, 0, stream>>>(S1, S2, pT2, weight, bias,
                                           gate_logits, diag_proj, A, B);
    apply_kernel<<<2048, 256, 0, stream>>>((const float4*)x, A, B, (float4*)out);
}